// Round 12
// baseline (224.864 us; speedup 1.0000x reference)
//
#include <hip/hip_runtime.h>
#include <stdint.h>

// Geometry (fixed): B=4, C=512, H=W=64
#define NB 4
#define CB 512
#define HH 64
#define WW 64
#define HW 4096
#define C4 2048
#define PTOT (NB*HW)   // 16384 pixels across batch

typedef float  f32x4  __attribute__((ext_vector_type(4)));
typedef short  bf16x8 __attribute__((ext_vector_type(8)));

__device__ __forceinline__ float relu_f(float v){ return v > 0.f ? v : 0.f; }

__device__ __forceinline__ float bf2f(unsigned short u){
    union { uint32_t i; float f; } v; v.i = ((uint32_t)u) << 16; return v.f;
}
__device__ __forceinline__ unsigned short f2bf(float f){
    union { float f; uint32_t i; } v; v.f = f;
    uint32_t r = v.i + 0x7FFFu + ((v.i >> 16) & 1u);   // RNE
    return (unsigned short)(r >> 16);
}

__device__ __forceinline__ void gload16(const void* g, void* l){
    __builtin_amdgcn_global_load_lds(
        (const __attribute__((address_space(1))) uint32_t*)g,
        (__attribute__((address_space(3))) uint32_t*)l, 16, 0, 0);
}

// ---------------------------------------------------------------------------
// Fused prep: blocks [0,2048) transpose+cast x -> xT ; blocks [2048,4352)
// cast the three weight matrices fp32 -> bf16 (one launch instead of two).
// ---------------------------------------------------------------------------
__global__ __launch_bounds__(256) void prep_fused(
    const float* __restrict__ x, unsigned short* __restrict__ xT,
    const float* __restrict__ a, unsigned short* __restrict__ oa,
    const float* __restrict__ b, unsigned short* __restrict__ ob,
    const float* __restrict__ c, unsigned short* __restrict__ oc)
{
    const int t = threadIdx.x;
    if (blockIdx.x >= 2048) {
        int i = (blockIdx.x - 2048) * 256 + t;
        const float* src; unsigned short* dst; int j;
        if (i < 65536)        { src = a; dst = oa; j = i; }
        else if (i < 327680)  { src = b; dst = ob; j = i - 65536; }
        else                  { src = c; dst = oc; j = i - 327680; }
        float4 v = ((const float4*)src)[j];
        ushort4 o;
        o.x = f2bf(v.x); o.y = f2bf(v.y); o.z = f2bf(v.z); o.w = f2bf(v.w);
        ((ushort4*)dst)[j] = o;
        return;
    }
    __shared__ unsigned short tile[64][72];
    const int tb = blockIdx.x;            // 0..2047
    const int p0 = (tb & 63) * 64;
    const int c0 = ((tb >> 6) & 7) * 64;
    const int bb = tb >> 9;

    const int pl = (t & 15) * 4;
    const int cl = t >> 4;
    const float* src = x + ((size_t)bb * CB + c0) * HW + p0;
    #pragma unroll
    for (int r = 0; r < 4; r++) {
        int c2 = cl + r * 16;
        float4 v = *(const float4*)(src + (size_t)c2 * HW + pl);
        tile[pl + 0][c2] = f2bf(v.x);
        tile[pl + 1][c2] = f2bf(v.y);
        tile[pl + 2][c2] = f2bf(v.z);
        tile[pl + 3][c2] = f2bf(v.w);
    }
    __syncthreads();
    unsigned short* dst = xT + ((size_t)bb * HW + p0) * CB + c0;
    const int cl2 = (t & 15) * 4;
    const int pl2 = t >> 4;
    #pragma unroll
    for (int r = 0; r < 4; r++) {
        int p = pl2 + r * 16;
        ushort4 o = *(ushort4*)&tile[p][cl2];
        *(ushort4*)(dst + (size_t)p * CB + cl2) = o;
    }
}

// ---------------------------------------------------------------------------
// Channel-last MFMA GEMM, B-operand in REGISTERS (LDS-BW fix):
//   D[p][o] = sum_k A[p][k] * Bw[o][k]  (bf16 in, f32 acc)
// Tile 128p x 128o, BK=64, 4 waves, 4x4 16x16x32 frags/wave.
// Diagnosis (R11): 16 ds_read_b128/wave/tile (A+B) = 128KB/CU/tile at
// ~85B/cy = ~1500cy vs 614cy MFMA -> LDS-read-BW bound (MfmaUtil capped
// ~40%, measured 30%). Fix: B (weights, L2-resident ~200cy) is loaded
// per-lane global->VGPR, double-set (bX/bY) prefetched 1 tile ahead.
// LDS holds only A (2 x 16K dbuf) -> LDS reads halve.
// vmcnt ledger (issue A(t+1) x4 gload_lds then B(t+1) x8 per tile):
//   at wait: [A(t)4,B(t)8,A(t+1)4,B(t+1)8] -> vmcnt(12); tail vmcnt(0).
// Grid (128,4): 4 o-blocks of a p-panel are 128 apart, 128%8==0 -> same XCD.
// OUTMODE 0: bf16 [PTOT][512] channel-last; 1: fp32 [b][512][HW] + ReLU.
// ---------------------------------------------------------------------------
template<int K, int OUTMODE>
__global__ __launch_bounds__(256) void gemm_cl(
    const unsigned short* __restrict__ A,
    const unsigned short* __restrict__ Bw,
    void* __restrict__ out)
{
    __shared__ __align__(16) char lds[34048];   // A dbuf 32K | epi f32[64][132]

    const int t    = threadIdx.x;
    const int lane = t & 63;
    const int wid  = t >> 6;
    const int p0   = blockIdx.x * 128;
    const int o0   = blockIdx.y * 128;

    const int l15 = lane & 15;
    const int l4  = lane >> 4;
    const int wp  = (wid & 1) * 64;
    const int wo  = (wid >> 1) * 64;
    const int rowA = wp + l15;
    const int swzA = (rowA & 7) << 4;

    f32x4 acc[4][4];
    #pragma unroll
    for (int m = 0; m < 4; m++)
        #pragma unroll
        for (int n = 0; n < 4; n++) acc[m][n] = (f32x4)0.f;

    const int srow  = t >> 3;          // 0..31 (+q*32)
    const int scolb = (t & 7) * 16;    // byte col in 128B row

    // A staging: gload_lds, linear LDS dest, pre-swizzled global source
    auto A_STAGE = [&](int k0, int aoff) {
        #pragma unroll
        for (int q = 0; q < 4; q++) {
            const int row = q * 32 + srow;
            const int kk  = k0 + ((scolb ^ ((row & 7) << 4)) >> 1);
            gload16(A + (size_t)(p0 + row) * K + kk,
                    lds + aoff + q * 4096 + wid * 1024);
        }
    };

    // B fragments: per-lane global loads (L2-resident weights).
    // Lane layout for mfma B-operand == A-operand: row = o (l15), 8 k-elems
    // at k0 + kh*32 + l4*8. Rows 16B apart per n; 4 l4 segs are 64B-contig.
    const unsigned short* bptr = Bw + (size_t)(o0 + wo + l15) * K + l4 * 8;
    auto B_LOAD = [&](int k0, bf16x8 (&bs)[8]) {
        #pragma unroll
        for (int kh = 0; kh < 2; kh++)
            #pragma unroll
            for (int n = 0; n < 4; n++)
                bs[kh * 4 + n] = *(const bf16x8*)(bptr + (size_t)n * (16 * K)
                                                  + k0 + kh * 32);
    };

    auto COMPUTE = [&](int aoff, const bf16x8 (&bs)[8]) {
        #pragma unroll
        for (int kh = 0; kh < 2; kh++) {
            const int colb = kh * 64 + l4 * 16;
            bf16x8 a[4];
            #pragma unroll
            for (int m = 0; m < 4; m++)
                a[m] = *(const bf16x8*)(lds + aoff + (rowA + m * 16) * 128
                                        + (colb ^ swzA));
            __builtin_amdgcn_s_setprio(1);
            #pragma unroll
            for (int m = 0; m < 4; m++)
                #pragma unroll
                for (int n = 0; n < 4; n++)
                    acc[m][n] = __builtin_amdgcn_mfma_f32_16x16x32_bf16(
                                    a[m], bs[kh * 4 + n], acc[m][n], 0, 0, 0);
            __builtin_amdgcn_s_setprio(0);
        }
    };

    const int NT = K / 64;
    bf16x8 bX[8], bY[8];

    A_STAGE(0, 0);
    B_LOAD(0, bX);                     // 12 loads in flight

    auto TILE = [&](int tt, int cur, int nxt, bf16x8 (&bcur)[8], bf16x8 (&bnxt)[8]) {
        const bool more = (tt + 1 < NT);
        if (more) { A_STAGE((tt + 1) * 64, nxt); B_LOAD((tt + 1) * 64, bnxt); }
        if (more) asm volatile("s_waitcnt vmcnt(12)" ::: "memory");
        else      asm volatile("s_waitcnt vmcnt(0)"  ::: "memory");
        __builtin_amdgcn_s_barrier();            // A(tt) resident everywhere
        __builtin_amdgcn_sched_barrier(0);
        COMPUTE(cur, bcur);                      // prefetches stay in flight
        __builtin_amdgcn_s_barrier();            // all reads of cur done
    };

    #pragma unroll 1
    for (int tp = 0; tp < NT; tp += 2) {         // NT even (8 or 32)
        TILE(tp,     0,     16384, bX, bY);
        TILE(tp + 1, 16384, 0,     bY, bX);
    }

    if (OUTMODE == 0) {
        unsigned short* op = (unsigned short*)out;
        #pragma unroll
        for (int m = 0; m < 4; m++)
            #pragma unroll
            for (int r = 0; r < 4; r++) {
                const int p = p0 + wp + m * 16 + l4 * 4 + r;
                #pragma unroll
                for (int n = 0; n < 4; n++) {
                    const int o = wo + n * 16 + l15 + o0;
                    op[(size_t)p * CB + o] = f2bf(acc[m][n][r]);
                }
            }
    } else {
        __syncthreads();                   // protect LDS reuse vs last COMPUTE reads
        float (*tl)[132] = (float(*)[132])lds;   // 64*132*4 = 33792 <= 34048
        const int bb   = p0 >> 12;
        const int phw0 = p0 & (HW - 1);
        #pragma unroll
        for (int half = 0; half < 2; half++) {
            if ((wid >> 1) == half) {
                #pragma unroll
                for (int n = 0; n < 4; n++)
                    #pragma unroll
                    for (int m = 0; m < 4; m++)
                        #pragma unroll
                        for (int r = 0; r < 4; r++)
                            tl[n * 16 + l15][wp + m * 16 + l4 * 4 + r] = acc[m][n][r];
            }
            __syncthreads();
            const int orow = t >> 2;
            const int pseg = (t & 3) * 32;
            float* dst = (float*)out +
                ((size_t)(bb * CB + o0 + half * 64 + orow)) * HW + phw0 + pseg;
            #pragma unroll
            for (int j = 0; j < 8; j++) {
                float4 v = *(float4*)&tl[orow][pseg + j * 4];
                v.x = relu_f(v.x); v.y = relu_f(v.y); v.z = relu_f(v.z); v.w = relu_f(v.w);
                *(float4*)(dst + j * 4) = v;
            }
            __syncthreads();
        }
    }
}

// ---------------------------------------------------------------------------
// Fused 4-direction IRNN scan, channel-last, scalar channel per thread.
// grid (512, 4): blockIdx.y = dir (0=u,1=r,2=d,3=l). Depth-8 reg prefetch.
// ---------------------------------------------------------------------------
__global__ __launch_bounds__(256) void irnn_fused(
    const unsigned short* __restrict__ in, unsigned short* __restrict__ outc,
    const float* __restrict__ wu, const float* __restrict__ bu,
    const float* __restrict__ wr, const float* __restrict__ br,
    const float* __restrict__ wd, const float* __restrict__ bd,
    const float* __restrict__ wl, const float* __restrict__ bl)
{
    const int dir = blockIdx.y;
    const float* wv; const float* bv; int pstep, rev;
    if      (dir == 0) { wv = wu; bv = bu; pstep = 64; rev = 1; }  // up
    else if (dir == 1) { wv = wr; bv = br; pstep = 1;  rev = 0; }  // right
    else if (dir == 2) { wv = wd; bv = bd; pstep = 64; rev = 0; }  // down
    else               { wv = wl; bv = bl; pstep = 1;  rev = 1; }  // left
    const int dirOff = dir * 512;

    const int idx = blockIdx.x * 256 + threadIdx.x;  // 0..131071
    const int c = idx & 511;
    const int f = (idx >> 9) & 63;
    const int b = idx >> 15;
    const int fbase = (pstep == 64) ? f : f * 64;

    const float wc = wv[c], bc = bv[c];
    const int t0 = rev ? 63 : 0;
    const int dp = rev ? -pstep : pstep;
    const int istep = dp * CB;
    const int ostep = dp * C4;

    const unsigned short* ip = in   + ((size_t)b * HW + fbase + (size_t)t0 * pstep) * CB + c;
    unsigned short*       op = outc + ((size_t)b * HW + fbase + (size_t)t0 * pstep) * C4 + dirOff + c;

    float s = relu_f(bf2f(ip[0]));
    op[0] = 0;

    unsigned short v0 = ip[1*istep], v1 = ip[2*istep], v2 = ip[3*istep], v3 = ip[4*istep],
                   v4 = ip[5*istep], v5 = ip[6*istep], v6 = ip[7*istep], v7 = ip[8*istep];

#define DO(kk, vv) { s = relu_f(fmaf(s, wc, bc + bf2f(vv))); op[(kk)*ostep] = f2bf(s); }
    for (int g = 0; g < 6; ++g) {
        const int k0 = 1 + 8 * g;
        DO(k0+0, v0); v0 = ip[(k0+ 8)*istep];
        DO(k0+1, v1); v1 = ip[(k0+ 9)*istep];
        DO(k0+2, v2); v2 = ip[(k0+10)*istep];
        DO(k0+3, v3); v3 = ip[(k0+11)*istep];
        DO(k0+4, v4); v4 = ip[(k0+12)*istep];
        DO(k0+5, v5); v5 = ip[(k0+13)*istep];
        DO(k0+6, v6); v6 = ip[(k0+14)*istep];
        DO(k0+7, v7); v7 = ip[(k0+15)*istep];
    }
    DO(49, v0); v0 = ip[57*istep];
    DO(50, v1); v1 = ip[58*istep];
    DO(51, v2); v2 = ip[59*istep];
    DO(52, v3); v3 = ip[60*istep];
    DO(53, v4); v4 = ip[61*istep];
    DO(54, v5); v5 = ip[62*istep];
    DO(55, v6); v6 = ip[63*istep];
    DO(56, v7);
    DO(57, v0); DO(58, v1); DO(59, v2); DO(60, v3);
    DO(61, v4); DO(62, v5); DO(63, v6);
#undef DO
}

// ---------------------------------------------------------------------------
// ws map: [0,16M) xT | [16M,80M) concat_T | [80M,96M) out0/mid |
//         [96M,..) bf16 weights. conv3x3 "attention" branch is dead -> skipped.
// 6 dispatches: prep | gemm512 | scan1 | gemm2048 | scan2 | gemm2048+relu.
// ---------------------------------------------------------------------------
extern "C" void kernel_launch(void* const* d_in, const int* in_sizes, int n_in,
                              void* d_out, int out_size, void* d_ws, size_t ws_size,
                              hipStream_t stream) {
    const float* x     = (const float*)d_in[0];
    const float* cin_w = (const float*)d_in[7];
    const float* c2_w  = (const float*)d_in[8];
    const float* c3_w  = (const float*)d_in[9];
    const float* i1_wu = (const float*)d_in[10];
    const float* i1_bu = (const float*)d_in[11];
    const float* i1_wr = (const float*)d_in[12];
    const float* i1_br = (const float*)d_in[13];
    const float* i1_wd = (const float*)d_in[14];
    const float* i1_bd = (const float*)d_in[15];
    const float* i1_wl = (const float*)d_in[16];
    const float* i1_bl = (const float*)d_in[17];
    const float* i2_wu = (const float*)d_in[18];
    const float* i2_bu = (const float*)d_in[19];
    const float* i2_wr = (const float*)d_in[20];
    const float* i2_br = (const float*)d_in[21];
    const float* i2_wd = (const float*)d_in[22];
    const float* i2_bd = (const float*)d_in[23];
    const float* i2_wl = (const float*)d_in[24];
    const float* i2_bl = (const float*)d_in[25];

    char* ws = (char*)d_ws;
    unsigned short* xT     = (unsigned short*)(ws);
    unsigned short* concat = (unsigned short*)(ws + (size_t)16 * 1024 * 1024);
    unsigned short* mid    = (unsigned short*)(ws + (size_t)80 * 1024 * 1024);
    unsigned short* wA     = (unsigned short*)(ws + (size_t)96 * 1024 * 1024);
    unsigned short* wB     = (unsigned short*)(wA + 512 * 512);
    unsigned short* wC     = (unsigned short*)(wB + 512 * 2048);

    // 1) prep: x transpose+cast AND weight casts in one launch
    prep_fused<<<4352, 256, 0, stream>>>(x, xT, cin_w, wA, c2_w, wB, c3_w, wC);

    dim3 ggrid(PTOT/128, 4);     // 128 x 4 = 512 blocks = 2/CU
    dim3 sgrid(512, 4);

    // 2) out0_T = xT @ cin_w^T
    gemm_cl<512, 0><<<ggrid, 256, 0, stream>>>(xT, wA, mid);

    // 3) IRNN #1 -> concat_T
    irnn_fused<<<sgrid, 256, 0, stream>>>(mid, concat,
        i1_wu, i1_bu, i1_wr, i1_br, i1_wd, i1_bd, i1_wl, i1_bl);

    // 4) mid_T = concat_T @ c2_w^T
    gemm_cl<2048, 0><<<ggrid, 256, 0, stream>>>(concat, wB, mid);

    // 5) IRNN #2 -> concat_T
    irnn_fused<<<sgrid, 256, 0, stream>>>(mid, concat,
        i2_wu, i2_bu, i2_wr, i2_br, i2_wd, i2_bd, i2_wl, i2_bl);

    // 6) d_out = relu(concat_T @ c3_w^T), fp32 channel-first
    gemm_cl<2048, 1><<<ggrid, 256, 0, stream>>>(concat, wC, d_out);
}

// Round 13
// 139.932 us; speedup vs baseline: 1.6070x; 1.6070x over previous
//
#include <hip/hip_runtime.h>
#include <stdint.h>

// Geometry (fixed): B=4, C=512, H=W=64
#define NB 4
#define CB 512
#define HH 64
#define WW 64
#define HW 4096
#define C4 2048
#define PTOT (NB*HW)   // 16384 pixels across batch

typedef float  f32x4  __attribute__((ext_vector_type(4)));
typedef short  bf16x8 __attribute__((ext_vector_type(8)));

__device__ __forceinline__ float relu_f(float v){ return v > 0.f ? v : 0.f; }

__device__ __forceinline__ float bf2f(unsigned short u){
    union { uint32_t i; float f; } v; v.i = ((uint32_t)u) << 16; return v.f;
}
__device__ __forceinline__ unsigned short f2bf(float f){
    union { float f; uint32_t i; } v; v.f = f;
    uint32_t r = v.i + 0x7FFFu + ((v.i >> 16) & 1u);   // RNE
    return (unsigned short)(r >> 16);
}

__device__ __forceinline__ void gload16(const void* g, void* l){
    __builtin_amdgcn_global_load_lds(
        (const __attribute__((address_space(1))) uint32_t*)g,
        (__attribute__((address_space(3))) uint32_t*)l, 16, 0, 0);
}

// ---------------------------------------------------------------------------
// Fused prep: blocks [0,2048) transpose+cast x -> xT ; blocks [2048,4352)
// cast the three weight matrices fp32 -> bf16 (one launch instead of two).
// ---------------------------------------------------------------------------
__global__ __launch_bounds__(256) void prep_fused(
    const float* __restrict__ x, unsigned short* __restrict__ xT,
    const float* __restrict__ a, unsigned short* __restrict__ oa,
    const float* __restrict__ b, unsigned short* __restrict__ ob,
    const float* __restrict__ c, unsigned short* __restrict__ oc)
{
    const int t = threadIdx.x;
    if (blockIdx.x >= 2048) {
        int i = (blockIdx.x - 2048) * 256 + t;
        const float* src; unsigned short* dst; int j;
        if (i < 65536)        { src = a; dst = oa; j = i; }
        else if (i < 327680)  { src = b; dst = ob; j = i - 65536; }
        else                  { src = c; dst = oc; j = i - 327680; }
        float4 v = ((const float4*)src)[j];
        ushort4 o;
        o.x = f2bf(v.x); o.y = f2bf(v.y); o.z = f2bf(v.z); o.w = f2bf(v.w);
        ((ushort4*)dst)[j] = o;
        return;
    }
    __shared__ unsigned short tile[64][72];
    const int tb = blockIdx.x;            // 0..2047
    const int p0 = (tb & 63) * 64;
    const int c0 = ((tb >> 6) & 7) * 64;
    const int bb = tb >> 9;

    const int pl = (t & 15) * 4;
    const int cl = t >> 4;
    const float* src = x + ((size_t)bb * CB + c0) * HW + p0;
    #pragma unroll
    for (int r = 0; r < 4; r++) {
        int c2 = cl + r * 16;
        float4 v = *(const float4*)(src + (size_t)c2 * HW + pl);
        tile[pl + 0][c2] = f2bf(v.x);
        tile[pl + 1][c2] = f2bf(v.y);
        tile[pl + 2][c2] = f2bf(v.z);
        tile[pl + 3][c2] = f2bf(v.w);
    }
    __syncthreads();
    unsigned short* dst = xT + ((size_t)bb * HW + p0) * CB + c0;
    const int cl2 = (t & 15) * 4;
    const int pl2 = t >> 4;
    #pragma unroll
    for (int r = 0; r < 4; r++) {
        int p = pl2 + r * 16;
        ushort4 o = *(ushort4*)&tile[p][cl2];
        *(ushort4*)(dst + (size_t)p * CB + cl2) = o;
    }
}

// ---------------------------------------------------------------------------
// Channel-last MFMA GEMM (R4 structure; session best after exploring the
// full neighborhood):  D[p][o] = sum_k A[p][k] * Bw[o][k]  (bf16, f32 acc)
// Tile 128p x 128o, BK=64, 4 waves, 4x4 16x16x32 frags/wave.
// LDS: 2 x (A 16K | B 16K) = 64K static -> 2 blocks/CU.
// Loop: STAGE(t+1) ; vmcnt(8) (drain only tile t's 8) ; barrier ; COMPUTE ;
// barrier. R13 micro-tune: (1) setprio REMOVED (m190: negative on lockstep
// 2-barrier structures); (2) all 16 fragment ds_reads of both K-halves
// hoisted ahead of the 32 MFMAs (LDS pipe streams; compiler's fine lgkmcnt
// lets early MFMAs overlap the tail reads).
// Grid (128,4): 4 o-blocks of a p-panel are 128 apart, 128%8==0 -> same XCD
// under default round-robin (A-panel L2 reuse for free).
// OUTMODE 0: bf16 [PTOT][512] channel-last; 1: fp32 [b][512][HW] + ReLU.
// ---------------------------------------------------------------------------
template<int K, int OUTMODE>
__global__ __launch_bounds__(256) void gemm_cl(
    const unsigned short* __restrict__ A,
    const unsigned short* __restrict__ Bw,
    void* __restrict__ out)
{
    __shared__ __align__(16) char lds[65536];

    const int t    = threadIdx.x;
    const int lane = t & 63;
    const int wid  = t >> 6;
    const int p0   = blockIdx.x * 128;
    const int o0   = blockIdx.y * 128;

    const int l15 = lane & 15;
    const int l4  = lane >> 4;
    const int wp  = (wid & 1) * 64;
    const int wo  = (wid >> 1) * 64;
    const int rowA = wp + l15;
    const int rowB = wo + l15;
    const int swzA = (rowA & 7) << 4;
    const int swzB = (rowB & 7) << 4;

    f32x4 acc[4][4];
    #pragma unroll
    for (int m = 0; m < 4; m++)
        #pragma unroll
        for (int n = 0; n < 4; n++) acc[m][n] = (f32x4)0.f;

    const int srow  = t >> 3;
    const int scolb = (t & 7) * 16;

    auto STAGE = [&](int k0, char* base) {
        #pragma unroll
        for (int q = 0; q < 4; q++) {
            const int row = q * 32 + srow;
            const int kk  = k0 + ((scolb ^ ((row & 7) << 4)) >> 1);
            gload16(A  + (size_t)(p0 + row) * K + kk, base +         q * 4096 + wid * 1024);
            gload16(Bw + (size_t)(o0 + row) * K + kk, base + 16384 + q * 4096 + wid * 1024);
        }
    };
    auto COMPUTE = [&](const char* base) {
        const char* cA = base;
        const char* cB = base + 16384;
        bf16x8 a2[2][4], b2[2][4];
        // hoist: issue all 16 fragment reads back-to-back
        #pragma unroll
        for (int kh = 0; kh < 2; kh++) {
            const int colb = kh * 64 + l4 * 16;
            #pragma unroll
            for (int m = 0; m < 4; m++)
                a2[kh][m] = *(const bf16x8*)(cA + (rowA + m * 16) * 128 + (colb ^ swzA));
            #pragma unroll
            for (int n = 0; n < 4; n++)
                b2[kh][n] = *(const bf16x8*)(cB + (rowB + n * 16) * 128 + (colb ^ swzB));
        }
        #pragma unroll
        for (int kh = 0; kh < 2; kh++)
            #pragma unroll
            for (int m = 0; m < 4; m++)
                #pragma unroll
                for (int n = 0; n < 4; n++)
                    acc[m][n] = __builtin_amdgcn_mfma_f32_16x16x32_bf16(
                                    a2[kh][m], b2[kh][n], acc[m][n], 0, 0, 0);
    };

    const int NT = K / 64;
    STAGE(0, lds);                                  // 8 loads in flight
    #pragma unroll 2
    for (int tt = 0; tt < NT - 1; ++tt) {
        char* cbase = lds + ((tt & 1) ? 32768 : 0);
        char* nbase = lds + ((tt & 1) ? 0 : 32768);
        STAGE((tt + 1) * 64, nbase);                // +8 loads (tile t+1)
        asm volatile("s_waitcnt vmcnt(8)" ::: "memory");  // drain ONLY tile t's 8
        __builtin_amdgcn_s_barrier();               // tile t resident everywhere
        __builtin_amdgcn_sched_barrier(0);
        COMPUTE(cbase);                             // MFMA current (prefetch in flight)
        __builtin_amdgcn_s_barrier();               // all reads of cbase done
    }
    asm volatile("s_waitcnt vmcnt(0)" ::: "memory");
    __builtin_amdgcn_s_barrier();
    __builtin_amdgcn_sched_barrier(0);
    COMPUTE(lds + (((NT - 1) & 1) ? 32768 : 0));

    if (OUTMODE == 0) {
        unsigned short* op = (unsigned short*)out;
        #pragma unroll
        for (int m = 0; m < 4; m++)
            #pragma unroll
            for (int r = 0; r < 4; r++) {
                const int p = p0 + wp + m * 16 + l4 * 4 + r;
                #pragma unroll
                for (int n = 0; n < 4; n++) {
                    const int o = wo + n * 16 + l15 + o0;
                    op[(size_t)p * CB + o] = f2bf(acc[m][n][r]);
                }
            }
    } else {
        __syncthreads();                   // protect LDS reuse vs last COMPUTE reads
        float (*tl)[132] = (float(*)[132])lds;
        const int bb   = p0 >> 12;
        const int phw0 = p0 & (HW - 1);
        #pragma unroll
        for (int half = 0; half < 2; half++) {
            if ((wid >> 1) == half) {
                #pragma unroll
                for (int n = 0; n < 4; n++)
                    #pragma unroll
                    for (int m = 0; m < 4; m++)
                        #pragma unroll
                        for (int r = 0; r < 4; r++)
                            tl[n * 16 + l15][wp + m * 16 + l4 * 4 + r] = acc[m][n][r];
            }
            __syncthreads();
            const int orow = t >> 2;
            const int pseg = (t & 3) * 32;
            float* dst = (float*)out +
                ((size_t)(bb * CB + o0 + half * 64 + orow)) * HW + phw0 + pseg;
            #pragma unroll
            for (int j = 0; j < 8; j++) {
                float4 v = *(float4*)&tl[orow][pseg + j * 4];
                v.x = relu_f(v.x); v.y = relu_f(v.y); v.z = relu_f(v.z); v.w = relu_f(v.w);
                *(float4*)(dst + j * 4) = v;
            }
            __syncthreads();
        }
    }
}

// ---------------------------------------------------------------------------
// Fused 4-direction IRNN scan, channel-last, scalar channel per thread.
// grid (512, 4): blockIdx.y = dir (0=u,1=r,2=d,3=l). Depth-8 reg prefetch.
// Traffic: 4x16MB read (L3-resident) + 64MB write -> ~13 us, at BW floor.
// ---------------------------------------------------------------------------
__global__ __launch_bounds__(256) void irnn_fused(
    const unsigned short* __restrict__ in, unsigned short* __restrict__ outc,
    const float* __restrict__ wu, const float* __restrict__ bu,
    const float* __restrict__ wr, const float* __restrict__ br,
    const float* __restrict__ wd, const float* __restrict__ bd,
    const float* __restrict__ wl, const float* __restrict__ bl)
{
    const int dir = blockIdx.y;
    const float* wv; const float* bv; int pstep, rev;
    if      (dir == 0) { wv = wu; bv = bu; pstep = 64; rev = 1; }  // up
    else if (dir == 1) { wv = wr; bv = br; pstep = 1;  rev = 0; }  // right
    else if (dir == 2) { wv = wd; bv = bd; pstep = 64; rev = 0; }  // down
    else               { wv = wl; bv = bl; pstep = 1;  rev = 1; }  // left
    const int dirOff = dir * 512;

    const int idx = blockIdx.x * 256 + threadIdx.x;  // 0..131071
    const int c = idx & 511;
    const int f = (idx >> 9) & 63;
    const int b = idx >> 15;
    const int fbase = (pstep == 64) ? f : f * 64;

    const float wc = wv[c], bc = bv[c];
    const int t0 = rev ? 63 : 0;
    const int dp = rev ? -pstep : pstep;
    const int istep = dp * CB;
    const int ostep = dp * C4;

    const unsigned short* ip = in   + ((size_t)b * HW + fbase + (size_t)t0 * pstep) * CB + c;
    unsigned short*       op = outc + ((size_t)b * HW + fbase + (size_t)t0 * pstep) * C4 + dirOff + c;

    float s = relu_f(bf2f(ip[0]));
    op[0] = 0;

    unsigned short v0 = ip[1*istep], v1 = ip[2*istep], v2 = ip[3*istep], v3 = ip[4*istep],
                   v4 = ip[5*istep], v5 = ip[6*istep], v6 = ip[7*istep], v7 = ip[8*istep];

#define DO(kk, vv) { s = relu_f(fmaf(s, wc, bc + bf2f(vv))); op[(kk)*ostep] = f2bf(s); }
    for (int g = 0; g < 6; ++g) {
        const int k0 = 1 + 8 * g;
        DO(k0+0, v0); v0 = ip[(k0+ 8)*istep];
        DO(k0+1, v1); v1 = ip[(k0+ 9)*istep];
        DO(k0+2, v2); v2 = ip[(k0+10)*istep];
        DO(k0+3, v3); v3 = ip[(k0+11)*istep];
        DO(k0+4, v4); v4 = ip[(k0+12)*istep];
        DO(k0+5, v5); v5 = ip[(k0+13)*istep];
        DO(k0+6, v6); v6 = ip[(k0+14)*istep];
        DO(k0+7, v7); v7 = ip[(k0+15)*istep];
    }
    DO(49, v0); v0 = ip[57*istep];
    DO(50, v1); v1 = ip[58*istep];
    DO(51, v2); v2 = ip[59*istep];
    DO(52, v3); v3 = ip[60*istep];
    DO(53, v4); v4 = ip[61*istep];
    DO(54, v5); v5 = ip[62*istep];
    DO(55, v6); v6 = ip[63*istep];
    DO(56, v7);
    DO(57, v0); DO(58, v1); DO(59, v2); DO(60, v3);
    DO(61, v4); DO(62, v5); DO(63, v6);
#undef DO
}

// ---------------------------------------------------------------------------
// ws map: [0,16M) xT | [16M,80M) concat_T | [80M,96M) out0/mid |
//         [96M,..) bf16 weights. conv3x3 "attention" branch is dead -> skipped.
// 6 dispatches: prep | gemm512 | scan1 | gemm2048 | scan2 | gemm2048+relu.
// ---------------------------------------------------------------------------
extern "C" void kernel_launch(void* const* d_in, const int* in_sizes, int n_in,
                              void* d_out, int out_size, void* d_ws, size_t ws_size,
                              hipStream_t stream) {
    const float* x     = (const float*)d_in[0];
    const float* cin_w = (const float*)d_in[7];
    const float* c2_w  = (const float*)d_in[8];
    const float* c3_w  = (const float*)d_in[9];
    const float* i1_wu = (const float*)d_in[10];
    const float* i1_bu = (const float*)d_in[11];
    const float* i1_wr = (const float*)d_in[12];
    const float* i1_br = (const float*)d_in[13];
    const float* i1_wd = (const float*)d_in[14];
    const float* i1_bd = (const float*)d_in[15];
    const float* i1_wl = (const float*)d_in[16];
    const float* i1_bl = (const float*)d_in[17];
    const float* i2_wu = (const float*)d_in[18];
    const float* i2_bu = (const float*)d_in[19];
    const float* i2_wr = (const float*)d_in[20];
    const float* i2_br = (const float*)d_in[21];
    const float* i2_wd = (const float*)d_in[22];
    const float* i2_bd = (const float*)d_in[23];
    const float* i2_wl = (const float*)d_in[24];
    const float* i2_bl = (const float*)d_in[25];

    char* ws = (char*)d_ws;
    unsigned short* xT     = (unsigned short*)(ws);
    unsigned short* concat = (unsigned short*)(ws + (size_t)16 * 1024 * 1024);
    unsigned short* mid    = (unsigned short*)(ws + (size_t)80 * 1024 * 1024);
    unsigned short* wA     = (unsigned short*)(ws + (size_t)96 * 1024 * 1024);
    unsigned short* wB     = (unsigned short*)(wA + 512 * 512);
    unsigned short* wC     = (unsigned short*)(wB + 512 * 2048);

    // 1) prep: x transpose+cast AND weight casts in one launch
    prep_fused<<<4352, 256, 0, stream>>>(x, xT, cin_w, wA, c2_w, wB, c3_w, wC);

    dim3 ggrid(PTOT/128, 4);     // 128 x 4 = 512 blocks = 2/CU
    dim3 sgrid(512, 4);

    // 2) out0_T = xT @ cin_w^T
    gemm_cl<512, 0><<<ggrid, 256, 0, stream>>>(xT, wA, mid);

    // 3) IRNN #1 -> concat_T
    irnn_fused<<<sgrid, 256, 0, stream>>>(mid, concat,
        i1_wu, i1_bu, i1_wr, i1_br, i1_wd, i1_bd, i1_wl, i1_bl);

    // 4) mid_T = concat_T @ c2_w^T
    gemm_cl<2048, 0><<<ggrid, 256, 0, stream>>>(concat, wB, mid);

    // 5) IRNN #2 -> concat_T
    irnn_fused<<<sgrid, 256, 0, stream>>>(mid, concat,
        i2_wu, i2_bu, i2_wr, i2_br, i2_wd, i2_bd, i2_wl, i2_bl);

    // 6) d_out = relu(concat_T @ c3_w^T), fp32 channel-first
    gemm_cl<2048, 1><<<ggrid, 256, 0, stream>>>(concat, wC, d_out);
}